// Round 1
// baseline (2601.980 us; speedup 1.0000x reference)
//
#include <hip/hip_runtime.h>
#include <hip/hip_bf16.h>

#define NN 100000
#define NE 100000
#define LP 136    // LDS pitch (bf16 elems) for K=128 tiles: 272B rows -> 2-way bank alias (free)
#define LP2 168   // LDS pitch for K=160 (meta)
#define EITER 8   // edges chunks per block in edge kernel (512 edges/block per W load)

typedef __bf16 bf16;
typedef __bf16 bf16x8 __attribute__((ext_vector_type(8)));
typedef float  f32x4  __attribute__((ext_vector_type(4)));

// ---------- helpers ----------

template<int PITCH, int COLS>
__device__ inline void stageWB(const bf16* __restrict__ Wg, bf16* Wl) {
    constexpr int NV = 128 * COLS / 8;
    for (int i = threadIdx.x; i < NV; i += 256) {
        const int e = i * 8;
        const int r = e / COLS, c = e % COLS;
        *(float4*)(&Wl[r * PITCH + c]) = ((const float4*)Wg)[i];
    }
}

__device__ inline void stageA(const bf16* __restrict__ A, bf16* Al, int row0) {
    const int r = threadIdx.x >> 2, q = threadIdx.x & 3;
    float4* d = (float4*)(&Al[r * LP + q * 32]);
    const int row = row0 + r;
    if (row < NN) {
        const float4* s = (const float4*)(A + (size_t)row * 128 + q * 32);
        float4 a0 = s[0], a1 = s[1], a2 = s[2], a3 = s[3];
        d[0] = a0; d[1] = a1; d[2] = a2; d[3] = a3;
    } else {
        float4 z = {0.f, 0.f, 0.f, 0.f};
        d[0] = z; d[1] = z; d[2] = z; d[3] = z;
    }
}

template<int PITCH, int KSTEPS>
__device__ inline void mmaT(const bf16* Al, const bf16* Wl, int m0, int lane, f32x4 acc[8]) {
#pragma unroll
    for (int kk = 0; kk < KSTEPS; ++kk) {
        bf16x8 a = *(const bf16x8*)(&Al[(m0 + (lane & 15)) * PITCH + kk * 32 + (lane >> 4) * 8]);
#pragma unroll
        for (int n = 0; n < 8; ++n) {
            bf16x8 b = *(const bf16x8*)(&Wl[(n * 16 + (lane & 15)) * PITCH + kk * 32 + (lane >> 4) * 8]);
            acc[n] = __builtin_amdgcn_mfma_f32_16x16x32_bf16(a, b, acc[n], 0, 0, 0);
        }
    }
}

__device__ inline void zacc(f32x4 acc[8]) {
    f32x4 z = {0.f, 0.f, 0.f, 0.f};
#pragma unroll
    for (int n = 0; n < 8; ++n) acc[n] = z;
}

// per-wave GroupNorm(1) stats: wave holds 16 full rows; rows (lane>>4)*4+r
__device__ inline void gnstats(const f32x4 acc[8], float mean[4], float rs[4]) {
    float s1[4], s2[4];
#pragma unroll
    for (int r = 0; r < 4; ++r) { s1[r] = 0.f; s2[r] = 0.f; }
#pragma unroll
    for (int n = 0; n < 8; ++n)
#pragma unroll
        for (int r = 0; r < 4; ++r) { float v = acc[n][r]; s1[r] += v; s2[r] += v * v; }
#pragma unroll
    for (int off = 1; off < 16; off <<= 1) {
#pragma unroll
        for (int r = 0; r < 4; ++r) {
            s1[r] += __shfl_xor(s1[r], off, 64);
            s2[r] += __shfl_xor(s2[r], off, 64);
        }
    }
#pragma unroll
    for (int r = 0; r < 4; ++r) {
        const float m = s1[r] * 0.0078125f;
        const float v = fmaxf(s2[r] * 0.0078125f - m * m, 0.f);
        mean[r] = m;
        rs[r] = rsqrtf(v + 1e-5f);
    }
}

// ---------- weight conversion ----------

__global__ void k_cvt(const float* __restrict__ s, bf16* __restrict__ d, int n) {
    for (int i = blockIdx.x * 256 + threadIdx.x; i < n; i += gridDim.x * 256)
        d[i] = (bf16)s[i];
}

__global__ void k_cvt_meta(const float* __restrict__ s, bf16* __restrict__ d) {
    for (int i = blockIdx.x * 256 + threadIdx.x; i < 128 * 160; i += gridDim.x * 256) {
        const int r = i / 160, c = i % 160;
        d[i] = (bf16)(c < 132 ? s[r * 132 + c] : 0.f);
    }
}

// ---------- input encoder: feat_pre = relu(gn(h1@in2^T) + gn(h2@seg2^T)) ----------

__global__ __launch_bounds__(256) void k_in(
    const float* __restrict__ nodes,
    const float* __restrict__ in1W, const float* __restrict__ in1b,
    const bf16* __restrict__ wIn2,
    const float* __restrict__ ing, const float* __restrict__ inbg,
    const float* __restrict__ seg1W, const float* __restrict__ seg1b,
    const bf16* __restrict__ wSeg2,
    const float* __restrict__ segg, const float* __restrict__ segbg,
    bf16* __restrict__ outPre)
{
    __shared__ __align__(16) bf16 Wl[128 * LP];
    __shared__ __align__(16) bf16 Al[64 * LP];
    __shared__ float w0[128], w1[128], bb[128];
    __shared__ float xs[64][4];
    const int tid = threadIdx.x;
    const int row0 = blockIdx.x * 64;
    if (tid < 64) {
        const int row = row0 + tid;
        float4 x = {0.f, 0.f, 0.f, 0.f};
        if (row < NN) x = *(const float4*)(nodes + (size_t)row * 8);
        xs[tid][0] = x.x; xs[tid][1] = x.y; xs[tid][2] = x.z; xs[tid][3] = x.w;
    }
    if (tid < 128) { w0[tid] = in1W[tid * 2]; w1[tid] = in1W[tid * 2 + 1]; bb[tid] = in1b[tid]; }
    stageWB<LP, 128>(wIn2, Wl);
    __syncthreads();
    for (int i = tid; i < 64 * 128; i += 256) {
        const int r = i >> 7, j = i & 127;
        Al[r * LP + j] = (bf16)fmaxf(xs[r][0] * w0[j] + xs[r][1] * w1[j] + bb[j], 0.f);
    }
    __syncthreads();
    const int lane = tid & 63, m0 = (tid >> 6) * 16;
    f32x4 accP[8]; zacc(accP);
    mmaT<LP, 4>(Al, Wl, m0, lane, accP);
    __syncthreads();
    if (tid < 128) { w0[tid] = seg1W[tid * 2]; w1[tid] = seg1W[tid * 2 + 1]; bb[tid] = seg1b[tid]; }
    stageWB<LP, 128>(wSeg2, Wl);
    __syncthreads();
    for (int i = tid; i < 64 * 128; i += 256) {
        const int r = i >> 7, j = i & 127;
        Al[r * LP + j] = (bf16)fmaxf(xs[r][2] * w0[j] + xs[r][3] * w1[j] + bb[j], 0.f);
    }
    __syncthreads();
    f32x4 accQ[8]; zacc(accQ);
    mmaT<LP, 4>(Al, Wl, m0, lane, accQ);

    float mP[4], rP[4], mQ[4], rQ[4];
    gnstats(accP, mP, rP);
    gnstats(accQ, mQ, rQ);
    float gP[8], bP[8], gQ[8], bQ[8];
#pragma unroll
    for (int n = 0; n < 8; ++n) {
        const int c = n * 16 + (lane & 15);
        gP[n] = ing[c]; bP[n] = inbg[c]; gQ[n] = segg[c]; bQ[n] = segbg[c];
    }
#pragma unroll
    for (int r = 0; r < 4; ++r) {
        const int row = row0 + m0 + (lane >> 4) * 4 + r;
        if (row < NN) {
#pragma unroll
            for (int n = 0; n < 8; ++n) {
                const float yp = (accP[n][r] - mP[r]) * rP[r] * gP[n] + bP[n];
                const float yq = (accQ[n][r] - mQ[r]) * rQ[r] * gQ[n] + bQ[n];
                outPre[(size_t)row * 128 + n * 16 + (lane & 15)] = (bf16)fmaxf(yp + yq, 0.f);
            }
        }
    }
}

// ---------- meta: feat = relu(gn([pre|x4..7] @ metaW^T)) ----------

__global__ __launch_bounds__(256) void k_meta(
    const bf16* __restrict__ Apre, const float* __restrict__ nodes,
    const bf16* __restrict__ Wg,   // 128x160 bf16 (padded)
    const float* __restrict__ g, const float* __restrict__ bg,
    float* __restrict__ featF, bf16* __restrict__ featB)
{
    __shared__ __align__(16) bf16 Wl[128 * LP2];
    __shared__ __align__(16) bf16 Al[64 * LP2];
    const int row0 = blockIdx.x * 64;
    stageWB<LP2, 160>(Wg, Wl);
    {
        const int r = threadIdx.x >> 2, q = threadIdx.x & 3;
        float4* d = (float4*)(&Al[r * LP2 + q * 32]);
        const int row = row0 + r;
        if (row < NN) {
            const float4* s = (const float4*)(Apre + (size_t)row * 128 + q * 32);
            float4 a0 = s[0], a1 = s[1], a2 = s[2], a3 = s[3];
            d[0] = a0; d[1] = a1; d[2] = a2; d[3] = a3;
        } else {
            float4 z = {0.f, 0.f, 0.f, 0.f};
            d[0] = z; d[1] = z; d[2] = z; d[3] = z;
        }
    }
    if (threadIdx.x < 64) {
        const int rr = threadIdx.x, row = row0 + rr;
        bf16* d = &Al[rr * LP2 + 128];
        if (row < NN) {
            const float4 x = *(const float4*)(nodes + (size_t)row * 8 + 4);
            d[0] = (bf16)x.x; d[1] = (bf16)x.y; d[2] = (bf16)x.z; d[3] = (bf16)x.w;
        } else {
            d[0] = (bf16)0.f; d[1] = (bf16)0.f; d[2] = (bf16)0.f; d[3] = (bf16)0.f;
        }
#pragma unroll
        for (int c = 4; c < 32; ++c) d[c] = (bf16)0.f;
    }
    __syncthreads();
    const int lane = threadIdx.x & 63, m0 = (threadIdx.x >> 6) * 16;
    f32x4 acc[8]; zacc(acc);
    mmaT<LP2, 5>(Al, Wl, m0, lane, acc);

    float mean[4], rs[4];
    gnstats(acc, mean, rs);
    float gv[8], bv[8];
#pragma unroll
    for (int n = 0; n < 8; ++n) { const int c = n * 16 + (lane & 15); gv[n] = g[c]; bv[n] = bg[c]; }
#pragma unroll
    for (int r = 0; r < 4; ++r) {
        const int row = row0 + m0 + (lane >> 4) * 4 + r;
        if (row < NN) {
            const size_t off = (size_t)row * 128 + (lane & 15);
#pragma unroll
            for (int n = 0; n < 8; ++n) {
                const float y = (acc[n][r] - mean[r]) * rs[r] * gv[n] + bv[n];
                const float o = fmaxf(y, 0.f);
                featF[off + n * 16] = o;
                featB[off + n * 16] = (bf16)o;
            }
        }
    }
}

// ---------- dense GEMM, raw f32 out: temp = feat @ ctrW^T ----------

__global__ __launch_bounds__(256) void k_ctr(const bf16* __restrict__ A,
                                             const bf16* __restrict__ Wg,
                                             float* __restrict__ outF)
{
    __shared__ __align__(16) bf16 Wl[128 * LP];
    __shared__ __align__(16) bf16 Al[64 * LP];
    const int row0 = blockIdx.x * 64;
    stageWB<LP, 128>(Wg, Wl);
    stageA(A, Al, row0);
    __syncthreads();
    const int lane = threadIdx.x & 63, m0 = (threadIdx.x >> 6) * 16;
    f32x4 acc[8]; zacc(acc);
    mmaT<LP, 4>(Al, Wl, m0, lane, acc);
#pragma unroll
    for (int r = 0; r < 4; ++r) {
        const int row = row0 + m0 + (lane >> 4) * 4 + r;
        if (row < NN) {
            float* p = outF + (size_t)row * 128 + (lane & 15);
#pragma unroll
            for (int n = 0; n < 8; ++n) p[n * 16] = acc[n][r];
        }
    }
}

// ---------- edge messages: temp[dst] += feat[src] @ edgeW[t]^T (atomics) ----------

__global__ __launch_bounds__(256) void k_edge(const bf16* __restrict__ feat,
                                              const int* __restrict__ idx,
                                              const int* __restrict__ mask,
                                              const bf16* __restrict__ Wall,
                                              float* __restrict__ tempF)
{
    __shared__ __align__(16) bf16 Wl[128 * LP];
    __shared__ __align__(16) bf16 Al[64 * LP];
    const int t = blockIdx.y;
    stageWB<LP, 128>(Wall + (size_t)t * 16384, Wl);
    const int lim = min(NE, mask[t]);
    const int tid = threadIdx.x, lane = tid & 63, m0 = (tid >> 6) * 16;
    const int base = blockIdx.x * (64 * EITER);
    for (int it = 0; it < EITER; ++it) {
        const int e0 = base + it * 64;
        if (e0 >= lim) break;          // block-uniform
        __syncthreads();               // protect Al reuse (and first-iter W staging)
        {
            const int r = tid >> 2, q = tid & 3;
            const int ev = e0 + r;
            float4* d = (float4*)(&Al[r * LP + q * 32]);
            if (ev < lim) {
                const int s = idx[(size_t)ev * 28 + 2 * t + 1];
                const float4* sp = (const float4*)(feat + (size_t)s * 128 + q * 32);
                float4 a0 = sp[0], a1 = sp[1], a2 = sp[2], a3 = sp[3];
                d[0] = a0; d[1] = a1; d[2] = a2; d[3] = a3;
            } else {
                float4 z = {0.f, 0.f, 0.f, 0.f};
                d[0] = z; d[1] = z; d[2] = z; d[3] = z;
            }
        }
        __syncthreads();
        f32x4 acc[8]; zacc(acc);
        mmaT<LP, 4>(Al, Wl, m0, lane, acc);
#pragma unroll
        for (int r = 0; r < 4; ++r) {
            const int row = m0 + (lane >> 4) * 4 + r;
            const int ev = e0 + row;
            if (ev < lim) {
                const int dn = idx[(size_t)ev * 28 + 2 * t];
                float* tp = tempF + (size_t)dn * 128 + (lane & 15);
#pragma unroll
                for (int n = 0; n < 8; ++n) unsafeAtomicAdd(tp + n * 16, acc[n][r]);
            }
        }
    }
}

// ---------- row GroupNorm + relu over f32 temp -> bf16 ----------

__global__ __launch_bounds__(256) void k_gn(const float* __restrict__ x,
                                            const float* __restrict__ g,
                                            const float* __restrict__ bg,
                                            bf16* __restrict__ out)
{
    const int row = blockIdx.x * 4 + (threadIdx.x >> 6);
    if (row >= NN) return;
    const int l = threadIdx.x & 63;
    const float2 v = *(const float2*)(x + (size_t)row * 128 + 2 * l);
    float s1 = v.x + v.y;
    float s2 = v.x * v.x + v.y * v.y;
#pragma unroll
    for (int off = 1; off < 64; off <<= 1) {
        s1 += __shfl_xor(s1, off, 64);
        s2 += __shfl_xor(s2, off, 64);
    }
    const float m = s1 * 0.0078125f;
    const float var = fmaxf(s2 * 0.0078125f - m * m, 0.f);
    const float rs = rsqrtf(var + 1e-5f);
    const float2 gv = *(const float2*)(g + 2 * l);
    const float2 bv = *(const float2*)(bg + 2 * l);
    const float y0 = fmaxf((v.x - m) * rs * gv.x + bv.x, 0.f);
    const float y1 = fmaxf((v.y - m) * rs * gv.y + bv.y, 0.f);
    union { bf16 h[2]; ushort2 u; } cv;
    cv.h[0] = (bf16)y0; cv.h[1] = (bf16)y1;
    *(ushort2*)(out + (size_t)row * 128 + 2 * l) = cv.u;
}

// ---------- ctr2 GEMM + GN + residual + relu ----------

__global__ __launch_bounds__(256) void k_ctr2(const bf16* __restrict__ A,
                                              const bf16* __restrict__ Wg,
                                              const float* __restrict__ g,
                                              const float* __restrict__ bg,
                                              float* __restrict__ featF,
                                              bf16* __restrict__ featB)
{
    __shared__ __align__(16) bf16 Wl[128 * LP];
    __shared__ __align__(16) bf16 Al[64 * LP];
    const int row0 = blockIdx.x * 64;
    stageWB<LP, 128>(Wg, Wl);
    stageA(A, Al, row0);
    __syncthreads();
    const int lane = threadIdx.x & 63, m0 = (threadIdx.x >> 6) * 16;
    f32x4 acc[8]; zacc(acc);
    mmaT<LP, 4>(Al, Wl, m0, lane, acc);

    float mean[4], rs[4];
    gnstats(acc, mean, rs);
    float gv[8], bv[8];
#pragma unroll
    for (int n = 0; n < 8; ++n) { const int c = n * 16 + (lane & 15); gv[n] = g[c]; bv[n] = bg[c]; }
#pragma unroll
    for (int r = 0; r < 4; ++r) {
        const int row = row0 + m0 + (lane >> 4) * 4 + r;
        if (row < NN) {
            const size_t off = (size_t)row * 128 + (lane & 15);
#pragma unroll
            for (int n = 0; n < 8; ++n) {
                const float y = (acc[n][r] - mean[r]) * rs[r] * gv[n] + bv[n];
                const float o = fmaxf(y + featF[off + n * 16], 0.f);
                featF[off + n * 16] = o;
                featB[off + n * 16] = (bf16)o;
            }
        }
    }
}

// ---------- output copy ----------

__global__ void k_out(const float* __restrict__ featF, const float* __restrict__ nodes,
                      float* __restrict__ out)
{
    const size_t stride = (size_t)gridDim.x * 256;
    size_t tid = (size_t)blockIdx.x * 256 + threadIdx.x;
    for (size_t i = tid; i < 12800000 / 4; i += stride)
        ((float4*)out)[i] = ((const float4*)featF)[i];
    for (size_t j = tid; j < 200000; j += stride)
        out[12800000 + j] = nodes[(j >> 1) * 8 + (j & 1)];
}

// ---------- launch ----------

extern "C" void kernel_launch(void* const* d_in, const int* in_sizes, int n_in,
                              void* d_out, int out_size, void* d_ws, size_t ws_size,
                              hipStream_t stream) {
    const float* nodes  = (const float*)d_in[0];
    const int*   idx    = (const int*)d_in[1];
    const int*   mask   = (const int*)d_in[2];
    const float* in1W   = (const float*)d_in[3];
    const float* in1b   = (const float*)d_in[4];
    const float* in2W   = (const float*)d_in[5];
    const float* ing    = (const float*)d_in[6];
    const float* inbg   = (const float*)d_in[7];
    const float* seg1W  = (const float*)d_in[8];
    const float* seg1b  = (const float*)d_in[9];
    const float* seg2W  = (const float*)d_in[10];
    const float* segg   = (const float*)d_in[11];
    const float* segbg  = (const float*)d_in[12];
    const float* metaW  = (const float*)d_in[13];
    const float* metag  = (const float*)d_in[14];
    const float* metabg = (const float*)d_in[15];
    const float* ctrW   = (const float*)d_in[16];
    const float* edgeW  = (const float*)d_in[17];
    const float* normg  = (const float*)d_in[18];
    const float* normbg = (const float*)d_in[19];
    const float* ctr2W  = (const float*)d_in[20];
    const float* ctr2g  = (const float*)d_in[21];
    const float* ctr2bg = (const float*)d_in[22];
    float* out = (float*)d_out;

    char* w = (char*)d_ws;
    float* featF  = (float*)w; w += (size_t)NN * 128 * 4;
    float* tempF  = (float*)w; w += (size_t)NN * 128 * 4;
    bf16*  featB  = (bf16*)w;  w += (size_t)NN * 128 * 2;
    bf16*  feat2B = (bf16*)w;  w += (size_t)NN * 128 * 2;
    bf16*  preB   = (bf16*)w;  w += (size_t)NN * 128 * 2;
    bf16*  wIn2   = (bf16*)w;  w += 16384 * 2;
    bf16*  wSeg2  = (bf16*)w;  w += 16384 * 2;
    bf16*  wMeta  = (bf16*)w;  w += 20480 * 2;
    bf16*  wCtr   = (bf16*)w;  w += 65536 * 2;
    bf16*  wCtr2  = (bf16*)w;  w += 65536 * 2;
    bf16*  wEdge  = (bf16*)w;  w += (size_t)917504 * 2;

    dim3 blk(256);
    const int gRows = (NN + 63) / 64;

    k_cvt<<<64, blk, 0, stream>>>(in2W, wIn2, 16384);
    k_cvt<<<64, blk, 0, stream>>>(seg2W, wSeg2, 16384);
    k_cvt_meta<<<80, blk, 0, stream>>>(metaW, wMeta);
    k_cvt<<<256, blk, 0, stream>>>(ctrW, wCtr, 65536);
    k_cvt<<<256, blk, 0, stream>>>(ctr2W, wCtr2, 65536);
    k_cvt<<<2048, blk, 0, stream>>>(edgeW, wEdge, 917504);

    k_in<<<gRows, blk, 0, stream>>>(nodes, in1W, in1b, wIn2, ing, inbg,
                                    seg1W, seg1b, wSeg2, segg, segbg, preB);
    k_meta<<<gRows, blk, 0, stream>>>(preB, nodes, wMeta, metag, metabg, featF, featB);

    for (int i = 0; i < 4; ++i) {
        k_ctr<<<gRows, blk, 0, stream>>>(featB, wCtr + (size_t)i * 16384, tempF);
        dim3 ge((NE + 64 * EITER - 1) / (64 * EITER), 14);
        k_edge<<<ge, blk, 0, stream>>>(featB, idx, mask, wEdge + (size_t)i * 14 * 16384, tempF);
        k_gn<<<(NN + 3) / 4, blk, 0, stream>>>(tempF, normg + i * 128, normbg + i * 128, feat2B);
        k_ctr2<<<gRows, blk, 0, stream>>>(feat2B, wCtr2 + (size_t)i * 16384,
                                          ctr2g + i * 128, ctr2bg + i * 128, featF, featB);
    }
    k_out<<<4096, blk, 0, stream>>>(featF, nodes, out);
}

// Round 2
// 1271.680 us; speedup vs baseline: 2.0461x; 2.0461x over previous
//
#include <hip/hip_runtime.h>
#include <hip/hip_bf16.h>

#define NN 100000
#define NE 100000
#define NCNT (14 * NN)
#define LP 136    // LDS pitch (bf16 elems) for K=128 tiles
#define LP2 168   // LDS pitch for K=160 (meta)
#define SCAN_CHUNK 4096
#define NSCB ((NCNT + SCAN_CHUNK - 1) / SCAN_CHUNK)

typedef __bf16 bf16;
typedef __bf16 bf16x8 __attribute__((ext_vector_type(8)));
typedef float  f32x4  __attribute__((ext_vector_type(4)));

// ---------- helpers ----------

template<int PITCH, int COLS>
__device__ inline void stageWB(const bf16* __restrict__ Wg, bf16* Wl) {
    constexpr int NV = 128 * COLS / 8;
    for (int i = threadIdx.x; i < NV; i += 256) {
        const int e = i * 8;
        const int r = e / COLS, c = e % COLS;
        *(float4*)(&Wl[r * PITCH + c]) = ((const float4*)Wg)[i];
    }
}

__device__ inline void stageA(const bf16* __restrict__ A, bf16* Al, int row0) {
    const int r = threadIdx.x >> 2, q = threadIdx.x & 3;
    float4* d = (float4*)(&Al[r * LP + q * 32]);
    const int row = row0 + r;
    if (row < NN) {
        const float4* s = (const float4*)(A + (size_t)row * 128 + q * 32);
        float4 a0 = s[0], a1 = s[1], a2 = s[2], a3 = s[3];
        d[0] = a0; d[1] = a1; d[2] = a2; d[3] = a3;
    } else {
        float4 z = {0.f, 0.f, 0.f, 0.f};
        d[0] = z; d[1] = z; d[2] = z; d[3] = z;
    }
}

template<int PITCH, int KSTEPS>
__device__ inline void mmaT(const bf16* Al, const bf16* Wl, int m0, int lane, f32x4 acc[8]) {
#pragma unroll
    for (int kk = 0; kk < KSTEPS; ++kk) {
        bf16x8 a = *(const bf16x8*)(&Al[(m0 + (lane & 15)) * PITCH + kk * 32 + (lane >> 4) * 8]);
#pragma unroll
        for (int n = 0; n < 8; ++n) {
            bf16x8 b = *(const bf16x8*)(&Wl[(n * 16 + (lane & 15)) * PITCH + kk * 32 + (lane >> 4) * 8]);
            acc[n] = __builtin_amdgcn_mfma_f32_16x16x32_bf16(a, b, acc[n], 0, 0, 0);
        }
    }
}

__device__ inline void zacc(f32x4 acc[8]) {
    f32x4 z = {0.f, 0.f, 0.f, 0.f};
#pragma unroll
    for (int n = 0; n < 8; ++n) acc[n] = z;
}

// per-wave GroupNorm(1) stats: wave holds 16 full rows; rows (lane>>4)*4+r
__device__ inline void gnstats(const f32x4 acc[8], float mean[4], float rs[4]) {
    float s1[4], s2[4];
#pragma unroll
    for (int r = 0; r < 4; ++r) { s1[r] = 0.f; s2[r] = 0.f; }
#pragma unroll
    for (int n = 0; n < 8; ++n)
#pragma unroll
        for (int r = 0; r < 4; ++r) { float v = acc[n][r]; s1[r] += v; s2[r] += v * v; }
#pragma unroll
    for (int off = 1; off < 16; off <<= 1) {
#pragma unroll
        for (int r = 0; r < 4; ++r) {
            s1[r] += __shfl_xor(s1[r], off, 64);
            s2[r] += __shfl_xor(s2[r], off, 64);
        }
    }
#pragma unroll
    for (int r = 0; r < 4; ++r) {
        const float m = s1[r] * 0.0078125f;
        const float v = fmaxf(s2[r] * 0.0078125f - m * m, 0.f);
        mean[r] = m;
        rs[r] = rsqrtf(v + 1e-5f);
    }
}

// ---------- weight conversion ----------

__global__ void k_cvt(const float* __restrict__ s, bf16* __restrict__ d, int n) {
    for (int i = blockIdx.x * 256 + threadIdx.x; i < n; i += gridDim.x * 256)
        d[i] = (bf16)s[i];
}

__global__ void k_cvt_meta(const float* __restrict__ s, bf16* __restrict__ d) {
    for (int i = blockIdx.x * 256 + threadIdx.x; i < 128 * 160; i += gridDim.x * 256) {
        const int r = i / 160, c = i % 160;
        d[i] = (bf16)(c < 132 ? s[r * 132 + c] : 0.f);
    }
}

// ---------- CSR build: count -> scan -> fill -> sort ----------

__global__ __launch_bounds__(256) void k_count(const int* __restrict__ idx,
                                               const int* __restrict__ mask,
                                               int* __restrict__ cnt) {
    __shared__ int lim[14];
    if (threadIdx.x < 14) lim[threadIdx.x] = min(mask[threadIdx.x], NE);
    __syncthreads();
    for (int i = blockIdx.x * 256 + threadIdx.x; i < 14 * NE; i += gridDim.x * 256) {
        const int e = i / 14, t = i - e * 14;
        if (e < lim[t]) atomicAdd(&cnt[t * NN + idx[(size_t)e * 28 + 2 * t]], 1);
    }
}

__global__ __launch_bounds__(256) void k_scanA(const int* __restrict__ cnt,
                                               int* __restrict__ ptr,
                                               int* __restrict__ tot) {
    __shared__ int sm[256];
    const int tid = threadIdx.x;
    const int base = blockIdx.x * SCAN_CHUNK + tid * 16;
    int v[16]; int run = 0;
#pragma unroll
    for (int j = 0; j < 16; ++j) {
        const int x = (base + j < NCNT) ? cnt[base + j] : 0;
        v[j] = run; run += x;
    }
    sm[tid] = run; __syncthreads();
    for (int d = 1; d < 256; d <<= 1) {
        int t = 0;
        if (tid >= d) t = sm[tid - d];
        __syncthreads();
        sm[tid] += t;
        __syncthreads();
    }
    const int off = sm[tid] - run;
#pragma unroll
    for (int j = 0; j < 16; ++j)
        if (base + j < NCNT) ptr[base + j] = v[j] + off;
    if (tid == 255) tot[blockIdx.x] = sm[255];
}

__global__ void k_scanB(int* __restrict__ tot) {
    if (threadIdx.x == 0 && blockIdx.x == 0) {
        int acc = 0;
        for (int b = 0; b < NSCB; ++b) { const int t = tot[b]; tot[b] = acc; acc += t; }
        tot[NSCB] = acc;
    }
}

__global__ __launch_bounds__(256) void k_scanC(int* __restrict__ ptr,
                                               int* __restrict__ cursor,
                                               const int* __restrict__ tot) {
    const int base = blockIdx.x * SCAN_CHUNK;
    const int o = tot[blockIdx.x];
    for (int j = threadIdx.x; j < SCAN_CHUNK; j += 256) {
        const int i = base + j;
        if (i < NCNT) { const int p = ptr[i] + o; ptr[i] = p; cursor[i] = p; }
    }
    if (blockIdx.x == 0 && threadIdx.x == 0) ptr[NCNT] = tot[NSCB];
}

__global__ __launch_bounds__(256) void k_fill(const int* __restrict__ idx,
                                              const int* __restrict__ mask,
                                              int* __restrict__ cursor,
                                              int* __restrict__ elist) {
    __shared__ int lim[14];
    if (threadIdx.x < 14) lim[threadIdx.x] = min(mask[threadIdx.x], NE);
    __syncthreads();
    for (int i = blockIdx.x * 256 + threadIdx.x; i < 14 * NE; i += gridDim.x * 256) {
        const int e = i / 14, t = i - e * 14;
        if (e < lim[t]) {
            const int dst = idx[(size_t)e * 28 + 2 * t];
            const int pos = atomicAdd(&cursor[t * NN + dst], 1);
            elist[pos] = e;
        }
    }
}

// sort each segment by edge id (determinism), then replace edge id -> src node id
__global__ __launch_bounds__(256) void k_sortseg(const int* __restrict__ ptr,
                                                 int* __restrict__ elist,
                                                 const int* __restrict__ idx) {
    for (int i = blockIdx.x * 256 + threadIdx.x; i < NCNT; i += gridDim.x * 256) {
        const int s = ptr[i], e2 = ptr[i + 1];
        for (int a = s + 1; a < e2; ++a) {
            const int key = elist[a];
            int b = a - 1;
            while (b >= s && elist[b] > key) { elist[b + 1] = elist[b]; --b; }
            elist[b + 1] = key;
        }
        const int t = i / NN;
        for (int j = s; j < e2; ++j)
            elist[j] = idx[(size_t)elist[j] * 28 + 2 * t + 1];
    }
}

// ---------- input encoder ----------

__global__ __launch_bounds__(256) void k_in(
    const float* __restrict__ nodes,
    const float* __restrict__ in1W, const float* __restrict__ in1b,
    const bf16* __restrict__ wIn2,
    const float* __restrict__ ing, const float* __restrict__ inbg,
    const float* __restrict__ seg1W, const float* __restrict__ seg1b,
    const bf16* __restrict__ wSeg2,
    const float* __restrict__ segg, const float* __restrict__ segbg,
    bf16* __restrict__ outPre)
{
    __shared__ __align__(16) bf16 Wl[128 * LP];
    __shared__ __align__(16) bf16 Al[64 * LP];
    __shared__ float w0[128], w1[128], bb[128];
    __shared__ float xs[64][4];
    const int tid = threadIdx.x;
    const int row0 = blockIdx.x * 64;
    if (tid < 64) {
        const int row = row0 + tid;
        float4 x = {0.f, 0.f, 0.f, 0.f};
        if (row < NN) x = *(const float4*)(nodes + (size_t)row * 8);
        xs[tid][0] = x.x; xs[tid][1] = x.y; xs[tid][2] = x.z; xs[tid][3] = x.w;
    }
    if (tid < 128) { w0[tid] = in1W[tid * 2]; w1[tid] = in1W[tid * 2 + 1]; bb[tid] = in1b[tid]; }
    stageWB<LP, 128>(wIn2, Wl);
    __syncthreads();
    for (int i = tid; i < 64 * 128; i += 256) {
        const int r = i >> 7, j = i & 127;
        Al[r * LP + j] = (bf16)fmaxf(xs[r][0] * w0[j] + xs[r][1] * w1[j] + bb[j], 0.f);
    }
    __syncthreads();
    const int lane = tid & 63, m0 = (tid >> 6) * 16;
    f32x4 accP[8]; zacc(accP);
    mmaT<LP, 4>(Al, Wl, m0, lane, accP);
    __syncthreads();
    if (tid < 128) { w0[tid] = seg1W[tid * 2]; w1[tid] = seg1W[tid * 2 + 1]; bb[tid] = seg1b[tid]; }
    stageWB<LP, 128>(wSeg2, Wl);
    __syncthreads();
    for (int i = tid; i < 64 * 128; i += 256) {
        const int r = i >> 7, j = i & 127;
        Al[r * LP + j] = (bf16)fmaxf(xs[r][2] * w0[j] + xs[r][3] * w1[j] + bb[j], 0.f);
    }
    __syncthreads();
    f32x4 accQ[8]; zacc(accQ);
    mmaT<LP, 4>(Al, Wl, m0, lane, accQ);

    float mP[4], rP[4], mQ[4], rQ[4];
    gnstats(accP, mP, rP);
    gnstats(accQ, mQ, rQ);
    float gP[8], bP[8], gQ[8], bQ[8];
#pragma unroll
    for (int n = 0; n < 8; ++n) {
        const int c = n * 16 + (lane & 15);
        gP[n] = ing[c]; bP[n] = inbg[c]; gQ[n] = segg[c]; bQ[n] = segbg[c];
    }
#pragma unroll
    for (int r = 0; r < 4; ++r) {
        const int row = row0 + m0 + (lane >> 4) * 4 + r;
        if (row < NN) {
#pragma unroll
            for (int n = 0; n < 8; ++n) {
                const float yp = (accP[n][r] - mP[r]) * rP[r] * gP[n] + bP[n];
                const float yq = (accQ[n][r] - mQ[r]) * rQ[r] * gQ[n] + bQ[n];
                outPre[(size_t)row * 128 + n * 16 + (lane & 15)] = (bf16)fmaxf(yp + yq, 0.f);
            }
        }
    }
}

// ---------- meta ----------

__global__ __launch_bounds__(256) void k_meta(
    const bf16* __restrict__ Apre, const float* __restrict__ nodes,
    const bf16* __restrict__ Wg,
    const float* __restrict__ g, const float* __restrict__ bg,
    float* __restrict__ featF, bf16* __restrict__ featB)
{
    __shared__ __align__(16) bf16 Wl[128 * LP2];
    __shared__ __align__(16) bf16 Al[64 * LP2];
    const int row0 = blockIdx.x * 64;
    stageWB<LP2, 160>(Wg, Wl);
    {
        const int r = threadIdx.x >> 2, q = threadIdx.x & 3;
        float4* d = (float4*)(&Al[r * LP2 + q * 32]);
        const int row = row0 + r;
        if (row < NN) {
            const float4* s = (const float4*)(Apre + (size_t)row * 128 + q * 32);
            float4 a0 = s[0], a1 = s[1], a2 = s[2], a3 = s[3];
            d[0] = a0; d[1] = a1; d[2] = a2; d[3] = a3;
        } else {
            float4 z = {0.f, 0.f, 0.f, 0.f};
            d[0] = z; d[1] = z; d[2] = z; d[3] = z;
        }
    }
    if (threadIdx.x < 64) {
        const int rr = threadIdx.x, row = row0 + rr;
        bf16* d = &Al[rr * LP2 + 128];
        if (row < NN) {
            const float4 x = *(const float4*)(nodes + (size_t)row * 8 + 4);
            d[0] = (bf16)x.x; d[1] = (bf16)x.y; d[2] = (bf16)x.z; d[3] = (bf16)x.w;
        } else {
            d[0] = (bf16)0.f; d[1] = (bf16)0.f; d[2] = (bf16)0.f; d[3] = (bf16)0.f;
        }
#pragma unroll
        for (int c = 4; c < 32; ++c) d[c] = (bf16)0.f;
    }
    __syncthreads();
    const int lane = threadIdx.x & 63, m0 = (threadIdx.x >> 6) * 16;
    f32x4 acc[8]; zacc(acc);
    mmaT<LP2, 5>(Al, Wl, m0, lane, acc);

    float mean[4], rs[4];
    gnstats(acc, mean, rs);
    float gv[8], bv[8];
#pragma unroll
    for (int n = 0; n < 8; ++n) { const int c = n * 16 + (lane & 15); gv[n] = g[c]; bv[n] = bg[c]; }
#pragma unroll
    for (int r = 0; r < 4; ++r) {
        const int row = row0 + m0 + (lane >> 4) * 4 + r;
        if (row < NN) {
            const size_t off = (size_t)row * 128 + (lane & 15);
#pragma unroll
            for (int n = 0; n < 8; ++n) {
                const float y = (acc[n][r] - mean[r]) * rs[r] * gv[n] + bv[n];
                const float o = fmaxf(y, 0.f);
                featF[off + n * 16] = o;
                featB[off + n * 16] = (bf16)o;
            }
        }
    }
}

// ---------- fused round: ctr + 14 edge-type gathered GEMMs + GN + ctr2 + GN + residual ----------

__global__ __launch_bounds__(256) void k_round(
    const bf16* __restrict__ feat,        // round input (bf16), NOT aliased with featOut
    const int* __restrict__ ptr,          // [NCNT+1] segment starts (global scan)
    const int* __restrict__ slist,        // [total] src node ids, dst-sorted
    const bf16* __restrict__ wEdgeR,      // 14 * 16384
    const bf16* __restrict__ wCtrR,       // 16384
    const bf16* __restrict__ wCtr2R,      // 16384
    const float* __restrict__ ng, const float* __restrict__ nbg,
    const float* __restrict__ c2g, const float* __restrict__ c2bg,
    float* __restrict__ featF,            // f32 residual master (in/out, row-local)
    bf16* __restrict__ featOut)           // round output (bf16)
{
    __shared__ __align__(16) bf16 Wl[128 * LP];
    __shared__ __align__(16) bf16 Al[64 * LP];
    const int tid = threadIdx.x, lane = tid & 63, m0 = (tid >> 6) * 16;
    const int row0 = blockIdx.x * 64;
    const int rr = tid >> 2, q = tid & 3;   // gather: 4 threads per dst row
    const int dst = row0 + rr;

    f32x4 acc[8]; zacc(acc);

    for (int t = 0; t < 14; ++t) {
        __syncthreads();   // previous MFMA done reading Al/Wl
        stageWB<LP, 128>(wEdgeR + (size_t)t * 16384, Wl);
        // gather-sum src features for this (t, dst), f32 accumulate
        float ag[32];
#pragma unroll
        for (int j = 0; j < 32; ++j) ag[j] = 0.f;
        if (dst < NN) {
            const int p0 = ptr[t * NN + dst], p1 = ptr[t * NN + dst + 1];
            for (int j = p0; j < p1; ++j) {
                const bf16x8* fp = (const bf16x8*)(feat + (size_t)slist[j] * 128 + q * 32);
                bf16x8 a0 = fp[0], a1 = fp[1], a2 = fp[2], a3 = fp[3];
#pragma unroll
                for (int k2 = 0; k2 < 8; ++k2) {
                    ag[k2]      += (float)a0[k2];
                    ag[8 + k2]  += (float)a1[k2];
                    ag[16 + k2] += (float)a2[k2];
                    ag[24 + k2] += (float)a3[k2];
                }
            }
        }
        bf16x8 ov[4];
#pragma unroll
        for (int v = 0; v < 4; ++v)
#pragma unroll
            for (int k2 = 0; k2 < 8; ++k2) ov[v][k2] = (bf16)ag[v * 8 + k2];
        bf16x8* dp = (bf16x8*)(&Al[rr * LP + q * 32]);
        dp[0] = ov[0]; dp[1] = ov[1]; dp[2] = ov[2]; dp[3] = ov[3];
        __syncthreads();
        mmaT<LP, 4>(Al, Wl, m0, lane, acc);
    }
    // t=14: ctr self-term
    __syncthreads();
    stageWB<LP, 128>(wCtrR, Wl);
    stageA(feat, Al, row0);
    __syncthreads();
    mmaT<LP, 4>(Al, Wl, m0, lane, acc);

    // epilogue 1: GN(norm_g/bg) + relu, write back into Al as bf16 A-tile
    float mean[4], rs[4];
    gnstats(acc, mean, rs);
    float gv[8], bv[8];
#pragma unroll
    for (int n = 0; n < 8; ++n) { const int c = n * 16 + (lane & 15); gv[n] = ng[c]; bv[n] = nbg[c]; }
    __syncthreads();   // all waves done with MFMA reads of Al/Wl
#pragma unroll
    for (int r = 0; r < 4; ++r) {
        const int lrow = m0 + (lane >> 4) * 4 + r;
#pragma unroll
        for (int n = 0; n < 8; ++n) {
            const float y = (acc[n][r] - mean[r]) * rs[r] * gv[n] + bv[n];
            Al[lrow * LP + n * 16 + (lane & 15)] = (bf16)fmaxf(y, 0.f);
        }
    }
    stageWB<LP, 128>(wCtr2R, Wl);
    __syncthreads();

    // phase 2: ctr2 GEMM
    zacc(acc);
    mmaT<LP, 4>(Al, Wl, m0, lane, acc);

    // epilogue 2: GN(ctr2) + residual + relu -> featF (f32) and featOut (bf16)
    gnstats(acc, mean, rs);
#pragma unroll
    for (int n = 0; n < 8; ++n) { const int c = n * 16 + (lane & 15); gv[n] = c2g[c]; bv[n] = c2bg[c]; }
#pragma unroll
    for (int r = 0; r < 4; ++r) {
        const int row = row0 + m0 + (lane >> 4) * 4 + r;
        if (row < NN) {
            const size_t off = (size_t)row * 128 + (lane & 15);
#pragma unroll
            for (int n = 0; n < 8; ++n) {
                const float y = (acc[n][r] - mean[r]) * rs[r] * gv[n] + bv[n];
                const float o = fmaxf(y + featF[off + n * 16], 0.f);
                featF[off + n * 16] = o;
                featOut[off + n * 16] = (bf16)o;
            }
        }
    }
}

// ---------- output copy ----------

__global__ void k_out(const float* __restrict__ featF, const float* __restrict__ nodes,
                      float* __restrict__ out)
{
    const size_t stride = (size_t)gridDim.x * 256;
    size_t tid = (size_t)blockIdx.x * 256 + threadIdx.x;
    for (size_t i = tid; i < 12800000 / 4; i += stride)
        ((float4*)out)[i] = ((const float4*)featF)[i];
    for (size_t j = tid; j < 200000; j += stride)
        out[12800000 + j] = nodes[(j >> 1) * 8 + (j & 1)];
}

// ---------- launch ----------

extern "C" void kernel_launch(void* const* d_in, const int* in_sizes, int n_in,
                              void* d_out, int out_size, void* d_ws, size_t ws_size,
                              hipStream_t stream) {
    const float* nodes  = (const float*)d_in[0];
    const int*   idx    = (const int*)d_in[1];
    const int*   mask   = (const int*)d_in[2];
    const float* in1W   = (const float*)d_in[3];
    const float* in1b   = (const float*)d_in[4];
    const float* in2W   = (const float*)d_in[5];
    const float* ing    = (const float*)d_in[6];
    const float* inbg   = (const float*)d_in[7];
    const float* seg1W  = (const float*)d_in[8];
    const float* seg1b  = (const float*)d_in[9];
    const float* seg2W  = (const float*)d_in[10];
    const float* segg   = (const float*)d_in[11];
    const float* segbg  = (const float*)d_in[12];
    const float* metaW  = (const float*)d_in[13];
    const float* metag  = (const float*)d_in[14];
    const float* metabg = (const float*)d_in[15];
    const float* ctrW   = (const float*)d_in[16];
    const float* edgeW  = (const float*)d_in[17];
    const float* normg  = (const float*)d_in[18];
    const float* normbg = (const float*)d_in[19];
    const float* ctr2W  = (const float*)d_in[20];
    const float* ctr2g  = (const float*)d_in[21];
    const float* ctr2bg = (const float*)d_in[22];
    float* out = (float*)d_out;

    char* w = (char*)d_ws;
    float* featF  = (float*)w; w += (size_t)NN * 128 * 4;
    bf16*  featB0 = (bf16*)w;  w += (size_t)NN * 128 * 2;
    bf16*  featB1 = (bf16*)w;  w += (size_t)NN * 128 * 2;
    bf16*  preB   = (bf16*)w;  w += (size_t)NN * 128 * 2;
    bf16*  wIn2   = (bf16*)w;  w += 16384 * 2;
    bf16*  wSeg2  = (bf16*)w;  w += 16384 * 2;
    bf16*  wMeta  = (bf16*)w;  w += 20480 * 2;
    bf16*  wCtr   = (bf16*)w;  w += 65536 * 2;
    bf16*  wCtr2  = (bf16*)w;  w += 65536 * 2;
    bf16*  wEdge  = (bf16*)w;  w += (size_t)917504 * 2;
    int*   cnt    = (int*)w;   w += (size_t)NCNT * 4;
    int*   ptr    = (int*)w;   w += ((size_t)NCNT + 4) * 4;
    int*   cursor = (int*)w;   w += (size_t)NCNT * 4;
    int*   elist  = (int*)w;   w += (size_t)14 * NE * 4;
    int*   tot    = (int*)w;   w += (NSCB + 1) * 4;

    dim3 blk(256);
    const int gRows = (NN + 63) / 64;

    // CSR build
    hipMemsetAsync(cnt, 0, (size_t)NCNT * 4, stream);
    k_count<<<2048, blk, 0, stream>>>(idx, mask, cnt);
    k_scanA<<<NSCB, blk, 0, stream>>>(cnt, ptr, tot);
    k_scanB<<<1, 64, 0, stream>>>(tot);
    k_scanC<<<NSCB, blk, 0, stream>>>(ptr, cursor, tot);
    k_fill<<<2048, blk, 0, stream>>>(idx, mask, cursor, elist);
    k_sortseg<<<2048, blk, 0, stream>>>(ptr, elist, idx);

    // weights -> bf16
    k_cvt<<<64, blk, 0, stream>>>(in2W, wIn2, 16384);
    k_cvt<<<64, blk, 0, stream>>>(seg2W, wSeg2, 16384);
    k_cvt_meta<<<80, blk, 0, stream>>>(metaW, wMeta);
    k_cvt<<<256, blk, 0, stream>>>(ctrW, wCtr, 65536);
    k_cvt<<<256, blk, 0, stream>>>(ctr2W, wCtr2, 65536);
    k_cvt<<<2048, blk, 0, stream>>>(edgeW, wEdge, 917504);

    // encoders
    k_in<<<gRows, blk, 0, stream>>>(nodes, in1W, in1b, wIn2, ing, inbg,
                                    seg1W, seg1b, wSeg2, segg, segbg, preB);
    k_meta<<<gRows, blk, 0, stream>>>(preB, nodes, wMeta, metag, metabg, featF, featB0);

    // 4 rounds, ping-pong bf16 feat buffers
    bf16* bufs[2] = { featB0, featB1 };
    for (int i = 0; i < 4; ++i) {
        k_round<<<gRows, blk, 0, stream>>>(bufs[i & 1], ptr, elist,
                                           wEdge + (size_t)i * 14 * 16384,
                                           wCtr + (size_t)i * 16384,
                                           wCtr2 + (size_t)i * 16384,
                                           normg + i * 128, normbg + i * 128,
                                           ctr2g + i * 128, ctr2bg + i * 128,
                                           featF, bufs[(i + 1) & 1]);
    }
    k_out<<<4096, blk, 0, stream>>>(featF, nodes, out);
}

// Round 3
// 1073.629 us; speedup vs baseline: 2.4235x; 1.1845x over previous
//
#include <hip/hip_runtime.h>
#include <hip/hip_bf16.h>

#define NN 100000
#define NE 100000
#define NCNT (14 * NN)
#define LP 136    // padded LDS pitch (bf16) for encoder kernels
#define LP2 168   // pitch for K=160 (meta)
#define SCAN_CHUNK 4096
#define NSCB ((NCNT + SCAN_CHUNK - 1) / SCAN_CHUNK)

typedef __bf16 bf16;
typedef __bf16 bf16x8 __attribute__((ext_vector_type(8)));
typedef float  f32x4  __attribute__((ext_vector_type(4)));

// ---------- generic helpers ----------

__device__ __forceinline__ void gl2lds16(const bf16* g, bf16* l) {
    __builtin_amdgcn_global_load_lds(
        (const __attribute__((address_space(1))) void*)g,
        (__attribute__((address_space(3))) void*)l, 16, 0, 0);
}

__device__ __forceinline__ void zacc8(f32x4 acc[8]) {
    f32x4 z = {0.f, 0.f, 0.f, 0.f};
#pragma unroll
    for (int n = 0; n < 8; ++n) acc[n] = z;
}

// per-wave GroupNorm(1) stats: wave holds 16 full rows; rows (lane>>4)*4+r
__device__ __forceinline__ void gnstats(const f32x4 acc[8], float mean[4], float rs[4]) {
    float s1[4], s2[4];
#pragma unroll
    for (int r = 0; r < 4; ++r) { s1[r] = 0.f; s2[r] = 0.f; }
#pragma unroll
    for (int n = 0; n < 8; ++n)
#pragma unroll
        for (int r = 0; r < 4; ++r) { float v = acc[n][r]; s1[r] += v; s2[r] += v * v; }
#pragma unroll
    for (int off = 1; off < 16; off <<= 1) {
#pragma unroll
        for (int r = 0; r < 4; ++r) {
            s1[r] += __shfl_xor(s1[r], off, 64);
            s2[r] += __shfl_xor(s2[r], off, 64);
        }
    }
#pragma unroll
    for (int r = 0; r < 4; ++r) {
        const float m = s1[r] * 0.0078125f;
        const float v = fmaxf(s2[r] * 0.0078125f - m * m, 0.f);
        mean[r] = m;
        rs[r] = rsqrtf(v + 1e-5f);
    }
}

// ---------- encoder-path helpers (padded-LDS reg staging) ----------

template<int PITCH, int COLS>
__device__ inline void stageWB(const bf16* __restrict__ Wg, bf16* Wl) {
    constexpr int NV = 128 * COLS / 8;
    for (int i = threadIdx.x; i < NV; i += 256) {
        const int e = i * 8;
        const int r = e / COLS, c = e % COLS;
        *(float4*)(&Wl[r * PITCH + c]) = ((const float4*)Wg)[i];
    }
}

template<int PITCH, int KSTEPS>
__device__ inline void mmaT(const bf16* Al, const bf16* Wl, int m0, int lane, f32x4 acc[8]) {
#pragma unroll
    for (int kk = 0; kk < KSTEPS; ++kk) {
        bf16x8 a = *(const bf16x8*)(&Al[(m0 + (lane & 15)) * PITCH + kk * 32 + (lane >> 4) * 8]);
#pragma unroll
        for (int n = 0; n < 8; ++n) {
            bf16x8 b = *(const bf16x8*)(&Wl[(n * 16 + (lane & 15)) * PITCH + kk * 32 + (lane >> 4) * 8]);
            acc[n] = __builtin_amdgcn_mfma_f32_16x16x32_bf16(a, b, acc[n], 0, 0, 0);
        }
    }
}

// ---------- k_round helpers ----------

// stage one 128x128 bf16 W into WLbase (linear rows of 256B, slot^=(row&7) swizzle)
// 8 waves x 4 instrs x 1024B = 32KB
__device__ __forceinline__ void stageW(const bf16* __restrict__ Wg, bf16* WLbase,
                                       int w, int lane) {
#pragma unroll
    for (int k = 0; k < 4; ++k) {
        const int R = (w * 4 + k) * 4 + (lane >> 4);
        const int sg = (lane & 15) ^ ((k & 1) * 4 + (lane >> 4));   // == (lane&15) ^ (R&7)
        gl2lds16(Wg + R * 128 + sg * 8, WLbase + (w * 4 + k) * 512);
    }
}

// B-frag reads from swizzled linear W tile + MFMA
__device__ __forceinline__ void mmaW(const bf16* B, const bf16x8 afr[4],
                                     int r, int h, int r7, f32x4 acc[8]) {
#pragma unroll
    for (int kk = 0; kk < 4; ++kk) {
        const int sl = ((kk * 4 + h) ^ r7) * 8;
#pragma unroll
        for (int n = 0; n < 8; ++n) {
            const bf16x8 b = *(const bf16x8*)(B + (n * 16 + r) * 128 + sl);
            acc[n] = __builtin_amdgcn_mfma_f32_16x16x32_bf16(afr[kk], b, acc[n], 0, 0, 0);
        }
    }
}

__device__ __forceinline__ void accum_row(const bf16* __restrict__ rp, float ag[4][8]) {
    const bf16x8* q = (const bf16x8*)rp;
    bf16x8 v0 = q[0], v1 = q[4], v2 = q[8], v3 = q[12];
#pragma unroll
    for (int e = 0; e < 8; ++e) {
        ag[0][e] += (float)v0[e];
        ag[1][e] += (float)v1[e];
        ag[2][e] += (float)v2[e];
        ag[3][e] += (float)v3[e];
    }
}

// ---------- weight conversion ----------

__global__ void k_cvt(const float* __restrict__ s, bf16* __restrict__ d, int n) {
    for (int i = blockIdx.x * 256 + threadIdx.x; i < n; i += gridDim.x * 256)
        d[i] = (bf16)s[i];
}

__global__ void k_cvt_meta(const float* __restrict__ s, bf16* __restrict__ d) {
    for (int i = blockIdx.x * 256 + threadIdx.x; i < 128 * 160; i += gridDim.x * 256) {
        const int r = i / 160, c = i % 160;
        d[i] = (bf16)(c < 132 ? s[r * 132 + c] : 0.f);
    }
}

// ---------- CSR build: count -> scan -> fill -> sort ----------

__global__ __launch_bounds__(256) void k_count(const int* __restrict__ idx,
                                               const int* __restrict__ mask,
                                               int* __restrict__ cnt) {
    __shared__ int lim[14];
    if (threadIdx.x < 14) lim[threadIdx.x] = min(mask[threadIdx.x], NE);
    __syncthreads();
    for (int i = blockIdx.x * 256 + threadIdx.x; i < 14 * NE; i += gridDim.x * 256) {
        const int e = i / 14, t = i - e * 14;
        if (e < lim[t]) atomicAdd(&cnt[t * NN + idx[(size_t)e * 28 + 2 * t]], 1);
    }
}

__global__ __launch_bounds__(256) void k_scanA(const int* __restrict__ cnt,
                                               int* __restrict__ ptr,
                                               int* __restrict__ tot) {
    __shared__ int sm[256];
    const int tid = threadIdx.x;
    const int base = blockIdx.x * SCAN_CHUNK + tid * 16;
    int v[16]; int run = 0;
#pragma unroll
    for (int j = 0; j < 16; ++j) {
        const int x = (base + j < NCNT) ? cnt[base + j] : 0;
        v[j] = run; run += x;
    }
    sm[tid] = run; __syncthreads();
    for (int d = 1; d < 256; d <<= 1) {
        int t = 0;
        if (tid >= d) t = sm[tid - d];
        __syncthreads();
        sm[tid] += t;
        __syncthreads();
    }
    const int off = sm[tid] - run;
#pragma unroll
    for (int j = 0; j < 16; ++j)
        if (base + j < NCNT) ptr[base + j] = v[j] + off;
    if (tid == 255) tot[blockIdx.x] = sm[255];
}

__global__ void k_scanB(int* __restrict__ tot) {
    if (threadIdx.x == 0 && blockIdx.x == 0) {
        int acc = 0;
        for (int b = 0; b < NSCB; ++b) { const int t = tot[b]; tot[b] = acc; acc += t; }
        tot[NSCB] = acc;
    }
}

__global__ __launch_bounds__(256) void k_scanC(int* __restrict__ ptr,
                                               int* __restrict__ cursor,
                                               const int* __restrict__ tot) {
    const int base = blockIdx.x * SCAN_CHUNK;
    const int o = tot[blockIdx.x];
    for (int j = threadIdx.x; j < SCAN_CHUNK; j += 256) {
        const int i = base + j;
        if (i < NCNT) { const int p = ptr[i] + o; ptr[i] = p; cursor[i] = p; }
    }
    if (blockIdx.x == 0 && threadIdx.x == 0) ptr[NCNT] = tot[NSCB];
}

__global__ __launch_bounds__(256) void k_fill(const int* __restrict__ idx,
                                              const int* __restrict__ mask,
                                              int* __restrict__ cursor,
                                              int* __restrict__ elist) {
    __shared__ int lim[14];
    if (threadIdx.x < 14) lim[threadIdx.x] = min(mask[threadIdx.x], NE);
    __syncthreads();
    for (int i = blockIdx.x * 256 + threadIdx.x; i < 14 * NE; i += gridDim.x * 256) {
        const int e = i / 14, t = i - e * 14;
        if (e < lim[t]) {
            const int dst = idx[(size_t)e * 28 + 2 * t];
            const int pos = atomicAdd(&cursor[t * NN + dst], 1);
            elist[pos] = e;
        }
    }
}

__global__ __launch_bounds__(256) void k_sortseg(const int* __restrict__ ptr,
                                                 int* __restrict__ elist,
                                                 const int* __restrict__ idx) {
    for (int i = blockIdx.x * 256 + threadIdx.x; i < NCNT; i += gridDim.x * 256) {
        const int s = ptr[i], e2 = ptr[i + 1];
        for (int a = s + 1; a < e2; ++a) {
            const int key = elist[a];
            int b = a - 1;
            while (b >= s && elist[b] > key) { elist[b + 1] = elist[b]; --b; }
            elist[b + 1] = key;
        }
        const int t = i / NN;
        for (int j = s; j < e2; ++j)
            elist[j] = idx[(size_t)elist[j] * 28 + 2 * t + 1];
    }
}

// ---------- input encoder ----------

__global__ __launch_bounds__(256) void k_in(
    const float* __restrict__ nodes,
    const float* __restrict__ in1W, const float* __restrict__ in1b,
    const bf16* __restrict__ wIn2,
    const float* __restrict__ ing, const float* __restrict__ inbg,
    const float* __restrict__ seg1W, const float* __restrict__ seg1b,
    const bf16* __restrict__ wSeg2,
    const float* __restrict__ segg, const float* __restrict__ segbg,
    bf16* __restrict__ outPre)
{
    __shared__ __align__(16) bf16 Wl[128 * LP];
    __shared__ __align__(16) bf16 Al[64 * LP];
    __shared__ float w0[128], w1[128], bb[128];
    __shared__ float xs[64][4];
    const int tid = threadIdx.x;
    const int row0 = blockIdx.x * 64;
    if (tid < 64) {
        const int row = row0 + tid;
        float4 x = {0.f, 0.f, 0.f, 0.f};
        if (row < NN) x = *(const float4*)(nodes + (size_t)row * 8);
        xs[tid][0] = x.x; xs[tid][1] = x.y; xs[tid][2] = x.z; xs[tid][3] = x.w;
    }
    if (tid < 128) { w0[tid] = in1W[tid * 2]; w1[tid] = in1W[tid * 2 + 1]; bb[tid] = in1b[tid]; }
    stageWB<LP, 128>(wIn2, Wl);
    __syncthreads();
    for (int i = tid; i < 64 * 128; i += 256) {
        const int r = i >> 7, j = i & 127;
        Al[r * LP + j] = (bf16)fmaxf(xs[r][0] * w0[j] + xs[r][1] * w1[j] + bb[j], 0.f);
    }
    __syncthreads();
    const int lane = tid & 63, m0 = (tid >> 6) * 16;
    f32x4 accP[8]; zacc8(accP);
    mmaT<LP, 4>(Al, Wl, m0, lane, accP);
    __syncthreads();
    if (tid < 128) { w0[tid] = seg1W[tid * 2]; w1[tid] = seg1W[tid * 2 + 1]; bb[tid] = seg1b[tid]; }
    stageWB<LP, 128>(wSeg2, Wl);
    __syncthreads();
    for (int i = tid; i < 64 * 128; i += 256) {
        const int r = i >> 7, j = i & 127;
        Al[r * LP + j] = (bf16)fmaxf(xs[r][2] * w0[j] + xs[r][3] * w1[j] + bb[j], 0.f);
    }
    __syncthreads();
    f32x4 accQ[8]; zacc8(accQ);
    mmaT<LP, 4>(Al, Wl, m0, lane, accQ);

    float mP[4], rP[4], mQ[4], rQ[4];
    gnstats(accP, mP, rP);
    gnstats(accQ, mQ, rQ);
    float gP[8], bP[8], gQ[8], bQ[8];
#pragma unroll
    for (int n = 0; n < 8; ++n) {
        const int c = n * 16 + (lane & 15);
        gP[n] = ing[c]; bP[n] = inbg[c]; gQ[n] = segg[c]; bQ[n] = segbg[c];
    }
#pragma unroll
    for (int r = 0; r < 4; ++r) {
        const int row = row0 + m0 + (lane >> 4) * 4 + r;
        if (row < NN) {
#pragma unroll
            for (int n = 0; n < 8; ++n) {
                const float yp = (accP[n][r] - mP[r]) * rP[r] * gP[n] + bP[n];
                const float yq = (accQ[n][r] - mQ[r]) * rQ[r] * gQ[n] + bQ[n];
                outPre[(size_t)row * 128 + n * 16 + (lane & 15)] = (bf16)fmaxf(yp + yq, 0.f);
            }
        }
    }
}

// ---------- meta ----------

__global__ __launch_bounds__(256) void k_meta(
    const bf16* __restrict__ Apre, const float* __restrict__ nodes,
    const bf16* __restrict__ Wg,
    const float* __restrict__ g, const float* __restrict__ bg,
    float* __restrict__ featF, bf16* __restrict__ featB)
{
    __shared__ __align__(16) bf16 Wl[128 * LP2];
    __shared__ __align__(16) bf16 Al[64 * LP2];
    const int row0 = blockIdx.x * 64;
    stageWB<LP2, 160>(Wg, Wl);
    {
        const int r = threadIdx.x >> 2, q = threadIdx.x & 3;
        float4* d = (float4*)(&Al[r * LP2 + q * 32]);
        const int row = row0 + r;
        if (row < NN) {
            const float4* s = (const float4*)(Apre + (size_t)row * 128 + q * 32);
            float4 a0 = s[0], a1 = s[1], a2 = s[2], a3 = s[3];
            d[0] = a0; d[1] = a1; d[2] = a2; d[3] = a3;
        } else {
            float4 z = {0.f, 0.f, 0.f, 0.f};
            d[0] = z; d[1] = z; d[2] = z; d[3] = z;
        }
    }
    if (threadIdx.x < 64) {
        const int rr = threadIdx.x, row = row0 + rr;
        bf16* d = &Al[rr * LP2 + 128];
        if (row < NN) {
            const float4 x = *(const float4*)(nodes + (size_t)row * 8 + 4);
            d[0] = (bf16)x.x; d[1] = (bf16)x.y; d[2] = (bf16)x.z; d[3] = (bf16)x.w;
        } else {
            d[0] = (bf16)0.f; d[1] = (bf16)0.f; d[2] = (bf16)0.f; d[3] = (bf16)0.f;
        }
#pragma unroll
        for (int c = 4; c < 32; ++c) d[c] = (bf16)0.f;
    }
    __syncthreads();
    const int lane = threadIdx.x & 63, m0 = (threadIdx.x >> 6) * 16;
    f32x4 acc[8]; zacc8(acc);
    mmaT<LP2, 5>(Al, Wl, m0, lane, acc);

    float mean[4], rs[4];
    gnstats(acc, mean, rs);
    float gv[8], bv[8];
#pragma unroll
    for (int n = 0; n < 8; ++n) { const int c = n * 16 + (lane & 15); gv[n] = g[c]; bv[n] = bg[c]; }
#pragma unroll
    for (int r = 0; r < 4; ++r) {
        const int row = row0 + m0 + (lane >> 4) * 4 + r;
        if (row < NN) {
            const size_t off = (size_t)row * 128 + (lane & 15);
#pragma unroll
            for (int n = 0; n < 8; ++n) {
                const float y = (acc[n][r] - mean[r]) * rs[r] * gv[n] + bv[n];
                const float o = fmaxf(y, 0.f);
                featF[off + n * 16] = o;
                featB[off + n * 16] = (bf16)o;
            }
        }
    }
}

// ---------- fused round, pipelined (M=128, 512 threads, reg gather, async W DMA) ----------

__global__ __launch_bounds__(512, 4) void k_round(
    const bf16* __restrict__ feat,
    const int* __restrict__ ptr,
    const int* __restrict__ slist,
    const bf16* __restrict__ wEdgeR,
    const bf16* __restrict__ wCtrR,
    const bf16* __restrict__ wCtr2R,
    const float* __restrict__ ng, const float* __restrict__ nbg,
    const float* __restrict__ c2g, const float* __restrict__ c2bg,
    float* __restrict__ featF,
    bf16* __restrict__ featOut,
    float* __restrict__ outF,
    int last)
{
    __shared__ __align__(16) bf16 WL[2 * 16384];
    const int tid = threadIdx.x;
    const int w = tid >> 6, lane = tid & 63;
    const int r = lane & 15, h = lane >> 4, r7 = r & 7;
    const int m0 = w * 16;
    const int row0 = blockIdx.x * 128;
    const int grow = row0 + m0 + r;            // row this lane gathers (A-side)
    const bool rowok = grow < NN;

    // prologue: async-stage W[0]
    stageW(wEdgeR, WL, w, lane);

    int p0 = 0, p1 = 0;
    if (rowok) { p0 = ptr[grow]; p1 = ptr[grow + 1]; }
    int sA = slist[p1 > p0 ? p0 : 0];

    f32x4 acc[8]; zacc8(acc);

    for (int t = 0; t < 15; ++t) {
        float ag[4][8];
#pragma unroll
        for (int kk = 0; kk < 4; ++kk)
#pragma unroll
            for (int e = 0; e < 8; ++e) ag[kk][e] = 0.f;

        if (t < 14) {
            if (rowok && p1 > p0) {
                accum_row(feat + (size_t)sA * 128 + h * 8, ag);
                for (int j = p0 + 1; j < p1; ++j)
                    accum_row(feat + (size_t)slist[j] * 128 + h * 8, ag);
            }
        } else if (rowok) {
            accum_row(feat + (size_t)grow * 128 + h * 8, ag);   // ctr self-term
        }

        // prefetch next type's segment (hides ptr->slist chain)
        if (t < 13) {
            int q0 = 0, q1 = 0;
            if (rowok) {
                const size_t i2 = (size_t)(t + 1) * NN + grow;
                q0 = ptr[i2]; q1 = ptr[i2 + 1];
            }
            const int sN = slist[q1 > q0 ? q0 : 0];
            p0 = q0; p1 = q1; sA = sN;
        }

        bf16x8 afr[4];
#pragma unroll
        for (int kk = 0; kk < 4; ++kk)
#pragma unroll
            for (int e = 0; e < 8; ++e) afr[kk][e] = (bf16)ag[kk][e];

        asm volatile("s_waitcnt vmcnt(0)" ::: "memory");   // my W[t] chunk + gathers landed
        __builtin_amdgcn_s_barrier();                      // all chunks in; all MFMA[t-1] reads done
        __builtin_amdgcn_sched_barrier(0);
        if (t < 13)       stageW(wEdgeR + (size_t)(t + 1) * 16384, WL + ((t + 1) & 1) * 16384, w, lane);
        else if (t == 13) stageW(wCtrR,  WL,          w, lane);   // t=14 uses buf0
        else              stageW(wCtr2R, WL + 16384,  w, lane);   // ctr2 into buf1
        __builtin_amdgcn_sched_barrier(0);
        mmaW(WL + (t & 1) * 16384, afr, r, h, r7, acc);
    }

    // epilogue 1: GN(norm) + relu -> swizzled bf16 A2 tile in WL[0..16383]
    float mean[4], rsv[4];
    gnstats(acc, mean, rsv);
    float gv[8], bv[8];
#pragma unroll
    for (int n = 0; n < 8; ++n) { const int c = n * 16 + r; gv[n] = ng[c]; bv[n] = nbg[c]; }
    asm volatile("s_waitcnt vmcnt(0)" ::: "memory");   // ctr2 W landed (mine)
    __builtin_amdgcn_s_barrier();                      // all MFMA[14] reads of buf0 done
    __builtin_amdgcn_sched_barrier(0);
#pragma unroll
    for (int r2 = 0; r2 < 4; ++r2) {
        const int lrow = m0 + h * 4 + r2;
#pragma unroll
        for (int n = 0; n < 8; ++n) {
            const float y = (acc[n][r2] - mean[r2]) * rsv[r2] * gv[n] + bv[n];
            const int col = n * 16 + r;
            const int slot = (col >> 3) ^ (lrow & 7);
            *(bf16*)((char*)WL + lrow * 256 + slot * 16 + (col & 7) * 2) = (bf16)fmaxf(y, 0.f);
        }
    }
    asm volatile("s_waitcnt lgkmcnt(0)" ::: "memory");
    __builtin_amdgcn_s_barrier();
    __builtin_amdgcn_sched_barrier(0);

    // phase 2: ctr2 GEMM (A2 from buf0-swizzled, W from buf1)
    bf16x8 afr2[4];
    {
        const int arow = m0 + r;
#pragma unroll
        for (int kk = 0; kk < 4; ++kk) {
            const int slot = (kk * 4 + h) ^ (arow & 7);
            afr2[kk] = *(const bf16x8*)((const char*)WL + arow * 256 + slot * 16);
        }
    }
    zacc8(acc);
    mmaW(WL + 16384, afr2, r, h, r7, acc);

    // epilogue 2: GN(ctr2) + residual + relu
    gnstats(acc, mean, rsv);
#pragma unroll
    for (int n = 0; n < 8; ++n) { const int c = n * 16 + r; gv[n] = c2g[c]; bv[n] = c2bg[c]; }
#pragma unroll
    for (int r2 = 0; r2 < 4; ++r2) {
        const int orow = row0 + m0 + h * 4 + r2;
        if (orow < NN) {
            const size_t off = (size_t)orow * 128 + r;
#pragma unroll
            for (int n = 0; n < 8; ++n) {
                const float y = (acc[n][r2] - mean[r2]) * rsv[r2] * gv[n] + bv[n];
                const float o = fmaxf(y + featF[off + n * 16], 0.f);
                if (last) {
                    outF[off + n * 16] = o;
                } else {
                    featF[off + n * 16] = o;
                    featOut[off + n * 16] = (bf16)o;
                }
            }
        }
    }
}

// ---------- nodes slice of the output ----------

__global__ void k_nodes(const float* __restrict__ nodes, float* __restrict__ out) {
    const int j = blockIdx.x * 256 + threadIdx.x;
    if (j < 2 * NN) out[(size_t)NN * 128 + j] = nodes[(size_t)(j >> 1) * 8 + (j & 1)];
}

// ---------- launch ----------

extern "C" void kernel_launch(void* const* d_in, const int* in_sizes, int n_in,
                              void* d_out, int out_size, void* d_ws, size_t ws_size,
                              hipStream_t stream) {
    const float* nodes  = (const float*)d_in[0];
    const int*   idx    = (const int*)d_in[1];
    const int*   mask   = (const int*)d_in[2];
    const float* in1W   = (const float*)d_in[3];
    const float* in1b   = (const float*)d_in[4];
    const float* in2W   = (const float*)d_in[5];
    const float* ing    = (const float*)d_in[6];
    const float* inbg   = (const float*)d_in[7];
    const float* seg1W  = (const float*)d_in[8];
    const float* seg1b  = (const float*)d_in[9];
    const float* seg2W  = (const float*)d_in[10];
    const float* segg   = (const float*)d_in[11];
    const float* segbg  = (const float*)d_in[12];
    const float* metaW  = (const float*)d_in[13];
    const float* metag  = (const float*)d_in[14];
    const float* metabg = (const float*)d_in[15];
    const float* ctrW   = (const float*)d_in[16];
    const float* edgeW  = (const float*)d_in[17];
    const float* normg  = (const float*)d_in[18];
    const float* normbg = (const float*)d_in[19];
    const float* ctr2W  = (const float*)d_in[20];
    const float* ctr2g  = (const float*)d_in[21];
    const float* ctr2bg = (const float*)d_in[22];
    float* out = (float*)d_out;

    char* w = (char*)d_ws;
    float* featF  = (float*)w; w += (size_t)NN * 128 * 4;
    bf16*  featB0 = (bf16*)w;  w += (size_t)NN * 128 * 2;
    bf16*  featB1 = (bf16*)w;  w += (size_t)NN * 128 * 2;
    bf16*  preB   = (bf16*)w;  w += (size_t)NN * 128 * 2;
    bf16*  wIn2   = (bf16*)w;  w += 16384 * 2;
    bf16*  wSeg2  = (bf16*)w;  w += 16384 * 2;
    bf16*  wMeta  = (bf16*)w;  w += 20480 * 2;
    bf16*  wCtr   = (bf16*)w;  w += 65536 * 2;
    bf16*  wCtr2  = (bf16*)w;  w += 65536 * 2;
    bf16*  wEdge  = (bf16*)w;  w += (size_t)917504 * 2;
    int*   cnt    = (int*)w;   w += (size_t)NCNT * 4;
    int*   ptr    = (int*)w;   w += ((size_t)NCNT + 4) * 4;
    int*   cursor = (int*)w;   w += (size_t)NCNT * 4;
    int*   elist  = (int*)w;   w += (size_t)14 * NE * 4;
    int*   tot    = (int*)w;   w += (NSCB + 1) * 4;

    dim3 blk(256);
    const int gRows = (NN + 63) / 64;

    // CSR build
    hipMemsetAsync(cnt, 0, (size_t)NCNT * 4, stream);
    k_count<<<2048, blk, 0, stream>>>(idx, mask, cnt);
    k_scanA<<<NSCB, blk, 0, stream>>>(cnt, ptr, tot);
    k_scanB<<<1, 64, 0, stream>>>(tot);
    k_scanC<<<NSCB, blk, 0, stream>>>(ptr, cursor, tot);
    k_fill<<<2048, blk, 0, stream>>>(idx, mask, cursor, elist);
    k_sortseg<<<2048, blk, 0, stream>>>(ptr, elist, idx);

    // weights -> bf16
    k_cvt<<<64, blk, 0, stream>>>(in2W, wIn2, 16384);
    k_cvt<<<64, blk, 0, stream>>>(seg2W, wSeg2, 16384);
    k_cvt_meta<<<80, blk, 0, stream>>>(metaW, wMeta);
    k_cvt<<<256, blk, 0, stream>>>(ctrW, wCtr, 65536);
    k_cvt<<<256, blk, 0, stream>>>(ctr2W, wCtr2, 65536);
    k_cvt<<<2048, blk, 0, stream>>>(edgeW, wEdge, 917504);

    // encoders
    k_in<<<gRows, blk, 0, stream>>>(nodes, in1W, in1b, wIn2, ing, inbg,
                                    seg1W, seg1b, wSeg2, segg, segbg, preB);
    k_meta<<<gRows, blk, 0, stream>>>(preB, nodes, wMeta, metag, metabg, featF, featB0);

    // 4 rounds, ping-pong bf16 feat buffers; last round writes d_out directly
    bf16* bufs[2] = { featB0, featB1 };
    const int gR2 = (NN + 127) / 128;
    for (int i = 0; i < 4; ++i) {
        k_round<<<gR2, dim3(512), 0, stream>>>(bufs[i & 1], ptr, elist,
                                               wEdge + (size_t)i * 14 * 16384,
                                               wCtr + (size_t)i * 16384,
                                               wCtr2 + (size_t)i * 16384,
                                               normg + i * 128, normbg + i * 128,
                                               ctr2g + i * 128, ctr2bg + i * 128,
                                               featF, bufs[(i + 1) & 1], out,
                                               i == 3 ? 1 : 0);
    }
    k_nodes<<<(2 * NN + 255) / 256, blk, 0, stream>>>(nodes, out);
}